// Round 12
// baseline (195.903 us; speedup 1.0000x reference)
//
#include <hip/hip_runtime.h>
#include <hip/hip_bf16.h>

typedef __bf16 bf16;
typedef __bf16 bf16x4 __attribute__((ext_vector_type(4)));
typedef __bf16 bf16x8 __attribute__((ext_vector_type(8)));
typedef float f32x4 __attribute__((ext_vector_type(4)));

#define AS1 __attribute__((address_space(1)))
#define AS3 __attribute__((address_space(3)))

__device__ __forceinline__ void gload_lds16(const void* g, void* l) {
  __builtin_amdgcn_global_load_lds((const AS1 void*)g, (AS3 void*)l, 16, 0, 0);
}

__device__ __forceinline__ float fexp2(float x) {
#if __has_builtin(__builtin_amdgcn_exp2f)
  return __builtin_amdgcn_exp2f(x);
#else
  return exp2f(x);
#endif
}

// ---------------- problem constants ----------------
#define BB 4
#define SS 2048
#define DD 1024
#define HH 16
#define MM (BB*SS)          // 8192 rows
#define LDQ 3072            // QKV fused row stride
#define NT (SS/64)          // K/V tiles per attention pass
#define NMASK4 (BB*SS*SS/4) // 4194304 int4
// log2(e) / sqrt(64)  -- folded into Wq,bq so softmax runs in exp2 domain
#define QSCALE 0.18033688011112042f

// ---------------- fused prep kernel ----------------
__global__ __launch_bounds__(256) void prep(
    const float* __restrict__ x, bf16* __restrict__ xb,
    const float* __restrict__ Wq, const float* __restrict__ Wk,
    const float* __restrict__ Wv, const float* __restrict__ Wo,
    bf16* __restrict__ WtQKV, bf16* __restrict__ Wto,
    const float* __restrict__ bq, const float* __restrict__ bk,
    const float* __restrict__ bv, float* __restrict__ ball,
    int* __restrict__ flag) {
  __shared__ float t[64][65];
  const int bid = blockIdx.x;
  if (bid < 1024) {            // ---- wtrans (heavy blocks first) ----
    int id = bid;
    int which = id >> 8;
    int bi = (id >> 4) & 15, bj = id & 15;   // bi: k-tile, bj: n-tile
    const float* W = which == 0 ? Wq : which == 1 ? Wk : which == 2 ? Wv : Wo;
    bf16* Wt = which < 3 ? WtQKV + (size_t)which * 1024 * DD : Wto;
    const float scale = (which == 0) ? QSCALE : 1.0f;
    for (int c = 0; c < 16; c++) {
      int idx = threadIdx.x + c * 256;
      int r = idx >> 6, col = idx & 63;
      t[r][col] = W[(size_t)(bi * 64 + r) * DD + bj * 64 + col];
    }
    __syncthreads();
    for (int c = 0; c < 16; c++) {
      int idx = threadIdx.x + c * 256;
      int rn = idx >> 6, ck = idx & 63;
      Wt[(size_t)(bj * 64 + rn) * DD + bi * 64 + ck] = (bf16)(t[ck][rn] * scale);
    }
  } else if (bid < 5120) {     // ---- cvt_x ----
    int i = ((bid - 1024) * 256 + threadIdx.x) * 8;
    float4 a = *(const float4*)&x[i];
    float4 b = *(const float4*)&x[i + 4];
    bf16x8 o;
    o[0] = (bf16)a.x; o[1] = (bf16)a.y; o[2] = (bf16)a.z; o[3] = (bf16)a.w;
    o[4] = (bf16)b.x; o[5] = (bf16)b.y; o[6] = (bf16)b.z; o[7] = (bf16)b.w;
    *(bf16x8*)&xb[i] = o;
  } else {                     // ---- bias concat + flag init ----
    int i = (bid - 5120) * 256 + threadIdx.x;
    if (i == 0) *flag = 1;
    float v = (i < 1024) ? bq[i] * QSCALE
                         : ((i < 2048) ? bk[i - 1024] : bv[i - 2048]);
    ball[i] = v;
  }
}

// ---------------- QKV GEMM: 256x256 8-phase schedule (T2+T3+T4+T5) ----------
// C(8192,3072) = A(8192,1024) @ Bt(3072,1024)^T + bias. Grid 384 x 512 thr
// (8 waves, 2M x 4N, per-wave 128x64). LDS 128 KiB: 2 slots x (A 256x64 +
// B 256x64) bf16, XOR slot-swizzle (write: pre-swizzled global source,
// linear LDS dest; read: slot ^ (row&7)).
// Per K-tile block j (4 phases, reading slot j&1):
//  phase 0: ds_read A-quad0(4) + B all(8); issue 2 mask int4; lgkmcnt(8)
//  phase 1: ds_read A-quad1(4); STAGE tile j+1 half-tile 3 (slot (j+1)&1)
//  phase 2: ds_read A-quad2(4)
//  phase 3: ds_read A-quad3(4); after MFMA: STAGE tile j+2 half-tiles 0..2
//           (slot j&1 -- all waves' reads done: pre-MFMA barrier passed),
//           vmcnt(6) -- retires tile j+1's 8 loads + this block's masks,
//           leaves 3 half-tiles in flight; consume masks.
//  each phase: barrier; lgkmcnt(0); setprio(1); 16 MFMA; setprio(0); barrier.
// Queue accounting per block: [j+1 h0h1h2(6)][masks(2)][j+1 h3(2)][j+2 h0h1h2(6)]
// -> vmcnt(6) retires first 10 = tile j+1 complete + masks.  Prologue: tile0
// (8 loads) + tile1 h0h1h2 (6), vmcnt(6) retires tile0. Epilogue: j=14 -> vmcnt(0).
__global__ __launch_bounds__(512, 2) void gemm_qkv_8ph(
    const bf16* __restrict__ A, const bf16* __restrict__ Bt,
    const float* __restrict__ bias, bf16* __restrict__ QKV,
    bf16* __restrict__ Vt, const int4* __restrict__ mask4,
    int* __restrict__ flag) {
  __shared__ bf16 lds[2][2][256 * 64];   // [slot][A=0/B=1][row*64 + e]
  const int tid = threadIdx.x;
  const int l = tid & 63;
  const int wid = tid >> 6, wr = wid >> 2, wc = wid & 3;

  // XCD-bijective swizzle (384 % 8 == 0): each XCD gets 4 consecutive by rows
  const int id = blockIdx.x;
  const int swz = (id & 7) * 48 + (id >> 3);
  const int by = swz / 12, bx = swz % 12;

  f32x4 acc[8][4] = {};

  // staging source (per-thread, fixed): row r0 in each 64-row round,
  // inverse-swizzled slot (XOR is an involution)
  const int r0 = tid >> 3;                       // 0..63
  const int se = ((tid & 7) ^ (r0 & 7)) * 8;     // source elem offset
  const bf16* aSrc = A + (size_t)(by * 256 + r0) * 1024 + se;
  const bf16* bSrc = Bt + (size_t)(bx * 256 + r0) * 1024 + se;
  const int dE = r0 * 64 + (tid & 7) * 8;        // LDS dest elem offset base

  int ok = 1;
  const int gthr = blockIdx.x * 512 + tid;

#define STAGE_HT(slot, j, ht)                                                \
  do {                                                                       \
    const bf16* s_ = ((ht) < 2 ? aSrc : bSrc);                               \
    const int h_ = (ht) & 1;                                                 \
    gload_lds16(s_ + (size_t)(h_ * 128) * 1024 + (j) * 64,                   \
                &lds[slot][(ht) >> 1][(h_ * 128) * 64 + dE]);                \
    gload_lds16(s_ + (size_t)(h_ * 128 + 64) * 1024 + (j) * 64,              \
                &lds[slot][(ht) >> 1][(h_ * 128 + 64) * 64 + dE]);           \
  } while (0)

  // prologue: tile0 fully + tile1 h0..h2; vmcnt(6); barrier
  STAGE_HT(0, 0, 0); STAGE_HT(0, 0, 1); STAGE_HT(0, 0, 2); STAGE_HT(0, 0, 3);
  STAGE_HT(1, 1, 0); STAGE_HT(1, 1, 1); STAGE_HT(1, 1, 2);
  asm volatile("s_waitcnt vmcnt(6)" ::: "memory");
  __builtin_amdgcn_s_barrier();

  for (int j = 0; j < 16; ++j) {
    const int s = j & 1;
    bf16x8 bfr[4][2];
    int4 mv0 = {1, 1, 1, 1}, mv1 = {1, 1, 1, 1};
    bool hv0 = false, hv1 = false;

    #pragma unroll
    for (int cq = 0; cq < 4; ++cq) {
      bf16x8 afr[2][2];
      #pragma unroll
      for (int m2 = 0; m2 < 2; ++m2) {
        int row = wr * 128 + (cq * 2 + m2) * 16 + (l & 15);
        #pragma unroll
        for (int kk = 0; kk < 2; ++kk) {
          int sl = (kk * 4 + (l >> 4)) ^ (l & 7);
          afr[m2][kk] = *(const bf16x8*)(&lds[s][0][row * 64 + sl * 8]);
        }
      }
      if (cq == 0) {
        #pragma unroll
        for (int ni = 0; ni < 4; ++ni) {
          int row = wc * 64 + ni * 16 + (l & 15);
          #pragma unroll
          for (int kk = 0; kk < 2; ++kk) {
            int sl = (kk * 4 + (l >> 4)) ^ (l & 7);
            bfr[ni][kk] = *(const bf16x8*)(&lds[s][1][row * 64 + sl * 8]);
          }
        }
        if (j <= 10) {   // 2 mask loads; retired by this block's vmcnt(6)
          int i0 = gthr + (j * 2) * 196608;
          int i1 = gthr + (j * 2 + 1) * 196608;
          hv0 = i0 < NMASK4;
          hv1 = i1 < NMASK4;
          if (hv0) mv0 = mask4[i0];
          if (hv1) mv1 = mask4[i1];
        }
        asm volatile("s_waitcnt lgkmcnt(8)" ::: "memory");
      }
      if (cq == 1 && j + 1 < 16) STAGE_HT((j + 1) & 1, j + 1, 3);

      __builtin_amdgcn_s_barrier();
      asm volatile("s_waitcnt lgkmcnt(0)" ::: "memory");
      __builtin_amdgcn_s_setprio(1);
      #pragma unroll
      for (int kk = 0; kk < 2; ++kk)
        #pragma unroll
        for (int m2 = 0; m2 < 2; ++m2)
          #pragma unroll
          for (int ni = 0; ni < 4; ++ni)
            acc[cq * 2 + m2][ni] = __builtin_amdgcn_mfma_f32_16x16x32_bf16(
                afr[m2][kk], bfr[ni][kk], acc[cq * 2 + m2][ni], 0, 0, 0);
      __builtin_amdgcn_s_setprio(0);

      if (cq == 3) {
        if (j + 2 < 16) {
          STAGE_HT(s, j + 2, 0);
          STAGE_HT(s, j + 2, 1);
          STAGE_HT(s, j + 2, 2);
          asm volatile("s_waitcnt vmcnt(6)" ::: "memory");
        } else if (j + 1 < 16) {
          asm volatile("s_waitcnt vmcnt(0)" ::: "memory");
        }
        if (hv0 && !(mv0.x && mv0.y && mv0.z && mv0.w)) ok = 0;
        if (hv1 && !(mv1.x && mv1.y && mv1.z && mv1.w)) ok = 0;
      }
      __builtin_amdgcn_s_barrier();
    }
  }
#undef STAGE_HT

  // epilogue: Q,K columns -> QKV rows; V columns (bx>=8) -> transposed Vt
  if (bx >= 8) {
    #pragma unroll
    for (int ni = 0; ni < 4; ++ni) {
      int col = bx * 256 + wc * 64 + ni * 16 + (l & 15);
      int n = col - 2048;
      float bb = bias[col];
      #pragma unroll
      for (int mi = 0; mi < 8; ++mi) {
        int row0 = by * 256 + wr * 128 + mi * 16 + (l >> 4) * 4;
        int b_ = row0 >> 11, s0 = row0 & 2047;
        bf16x4 vv;
        #pragma unroll
        for (int r = 0; r < 4; ++r) vv[r] = (bf16)(acc[mi][ni][r] + bb);
        *(bf16x4*)&Vt[(size_t)(b_ * 1024 + n) * SS + s0] = vv;
      }
    }
  } else {
    #pragma unroll
    for (int ni = 0; ni < 4; ++ni) {
      int col = bx * 256 + wc * 64 + ni * 16 + (l & 15);
      float bb = bias[col];
      #pragma unroll
      for (int mi = 0; mi < 8; ++mi) {
        int row0 = by * 256 + wr * 128 + mi * 16 + (l >> 4) * 4;
        #pragma unroll
        for (int r = 0; r < 4; ++r)
          QKV[(size_t)(row0 + r) * LDQ + col] = (bf16)(acc[mi][ni][r] + bb);
      }
    }
  }
  if (__ballot(!ok)) {
    if ((tid & 63) == 0) atomicAnd(flag, 0);
  }
}

// ---------------- out-proj GEMM (m97 128x128 structure, proven) -------------
__global__ __launch_bounds__(256) void gemm_out(const bf16* __restrict__ A,
                                                const bf16* __restrict__ Bt,
                                                const float* __restrict__ bias,
                                                float* __restrict__ Cout) {
  constexpr int K = 1024;
  constexpr int BM = 128, BN = 128, BK = 64;
  __shared__ bf16 As[BM * BK];
  __shared__ bf16 Bs[BN * BK];
  const int tid = threadIdx.x;
  const int w = tid >> 6, l = tid & 63;
  const int wm = w >> 1, wn = w & 1;
  const int by = blockIdx.x, bx = blockIdx.y;

  f32x4 acc[4][4] = {};

  const int sRow = l >> 3;
  const int sSlot = (l & 7) ^ sRow;
  const bf16* aBase = A + (size_t)(by * BM + w * 32 + sRow) * K + sSlot * 8;
  const bf16* bBase = Bt + (size_t)(bx * BN + w * 32 + sRow) * K + sSlot * 8;

  for (int k0 = 0; k0 < K; k0 += BK) {
    #pragma unroll
    for (int c = 0; c < 4; c++) {
      gload_lds16(aBase + (size_t)(c * 8) * K + k0, &As[(w * 32 + c * 8) * BK]);
      gload_lds16(bBase + (size_t)(c * 8) * K + k0, &Bs[(w * 32 + c * 8) * BK]);
    }
    __syncthreads();
    #pragma unroll
    for (int kk = 0; kk < 2; kk++) {
      bf16x8 af[4], bfr[4];
      #pragma unroll
      for (int i = 0; i < 4; i++) {
        int row = wm * 64 + i * 16 + (l & 15);
        int sl = (kk * 4 + (l >> 4)) ^ (row & 7);
        af[i] = *(const bf16x8*)(&As[row * BK + sl * 8]);
      }
      #pragma unroll
      for (int j = 0; j < 4; j++) {
        int row = wn * 64 + j * 16 + (l & 15);
        int sl = (kk * 4 + (l >> 4)) ^ (row & 7);
        bfr[j] = *(const bf16x8*)(&Bs[row * BK + sl * 8]);
      }
      #pragma unroll
      for (int i = 0; i < 4; i++)
        #pragma unroll
        for (int j = 0; j < 4; j++)
          acc[i][j] = __builtin_amdgcn_mfma_f32_16x16x32_bf16(af[i], bfr[j],
                                                              acc[i][j], 0, 0, 0);
    }
    __syncthreads();
  }

  #pragma unroll
  for (int j = 0; j < 4; j++) {
    int col = bx * BN + wn * 64 + j * 16 + (l & 15);
    float bb = bias[col];
    #pragma unroll
    for (int i = 0; i < 4; i++) {
      int row0 = by * BM + wm * 64 + i * 16 + (l >> 4) * 4;
      #pragma unroll
      for (int r = 0; r < 4; r++)
        Cout[(size_t)(row0 + r) * DD + col] = acc[i][j][r] + bb;
    }
  }
}

// ---------------- fused flash attention (R6 structure, proven 77 us) ---------
__global__ __launch_bounds__(256, 2) void attn_fwd(const bf16* __restrict__ QKV,
                                                   const bf16* __restrict__ Vt,
                                                   const int* __restrict__ mask,
                                                   const int* __restrict__ flag,
                                                   bf16* __restrict__ att) {
  __shared__ bf16 Ks[2][64 * 64];
  __shared__ bf16 Vs[2][64 * 64];
  const int tid = threadIdx.x, w = tid >> 6, l = tid & 63;
  const int g = l >> 4, q = l & 15;
  const int bh = blockIdx.x, b = bh >> 4, h = bh & 15;
  const int q0 = blockIdx.y * 256 + w * 64;   // this wave's 64 q-rows
  const bool allones = (*flag != 0);

  bf16x8 bq[4][2];
  #pragma unroll
  for (int qb = 0; qb < 4; qb++) {
    const bf16* qptr =
        QKV + (size_t)(b * SS + q0 + qb * 16 + q) * LDQ + h * 64 + g * 8;
    bq[qb][0] = *(const bf16x8*)qptr;
    bq[qb][1] = *(const bf16x8*)(qptr + 32);
  }

  bf16x8 ones;
  #pragma unroll
  for (int j = 0; j < 8; j++) ones[j] = (bf16)1.0f;

  f32x4 o[4][4] = {};
  f32x4 ls[4] = {};

  const int sSlot = (l & 7) ^ ((l >> 3) & 7);
  const bf16* kPtr[2];
  #pragma unroll
  for (int c = 0; c < 2; c++) {
    int B8 = 2 * w + c;
    int tl = 32 * (B8 >> 2) + 16 * (B8 & 1) + 4 * ((B8 >> 1) & 1) +
             8 * (l >> 5) + ((l >> 3) & 3);
    kPtr[c] = QKV + (size_t)(b * SS + tl) * LDQ + 1024 + h * 64 + sSlot * 8;
  }
  const bf16* vBase =
      Vt + (size_t)(b * 1024 + h * 64 + w * 16 + (l >> 3)) * SS + sSlot * 8;

  gload_lds16(kPtr[0], &Ks[0][(2 * w + 0) * 8 * 64]);
  gload_lds16(kPtr[1], &Ks[0][(2 * w + 1) * 8 * 64]);
  gload_lds16(vBase, &Vs[0][(w * 16) * 64]);
  gload_lds16(vBase + (size_t)8 * SS, &Vs[0][(w * 16 + 8) * 64]);

  for (int it = 0; it < NT; ++it) {
    const int cur = it & 1;
    if (it + 1 < NT) {
      const int t1 = (it + 1) * 64;
      gload_lds16(kPtr[0] + (size_t)t1 * LDQ, &Ks[cur ^ 1][(2 * w + 0) * 8 * 64]);
      gload_lds16(kPtr[1] + (size_t)t1 * LDQ, &Ks[cur ^ 1][(2 * w + 1) * 8 * 64]);
      gload_lds16(vBase + t1, &Vs[cur ^ 1][(w * 16) * 64]);
      gload_lds16(vBase + (size_t)8 * SS + t1, &Vs[cur ^ 1][(w * 16 + 8) * 64]);
      asm volatile("s_waitcnt vmcnt(4)" ::: "memory");
    } else {
      asm volatile("s_waitcnt vmcnt(0)" ::: "memory");
    }
    __builtin_amdgcn_s_barrier();
    asm volatile("" ::: "memory");

    const bf16* ks = Ks[cur];
    const bf16* vs = Vs[cur];

    bf16x8 af[4][2];
    #pragma unroll
    for (int tt = 0; tt < 4; tt++) {
      int row = tt * 16 + q;
      af[tt][0] = *(const bf16x8*)(&ks[row * 64 + (g ^ (q & 7)) * 8]);
      af[tt][1] = *(const bf16x8*)(&ks[row * 64 + (((4 + g) ^ (q & 7))) * 8]);
    }

    bf16x8 pb[4][2];
    #pragma unroll
    for (int qb = 0; qb < 4; qb++) {
      f32x4 s4[4];
      #pragma unroll
      for (int tt = 0; tt < 4; tt++) {
        f32x4 z = {};
        z = __builtin_amdgcn_mfma_f32_16x16x32_bf16(af[tt][0], bq[qb][0], z, 0, 0, 0);
        z = __builtin_amdgcn_mfma_f32_16x16x32_bf16(af[tt][1], bq[qb][1], z, 0, 0, 0);
        s4[tt] = z;
      }

      if (!allones) {
        const int t0 = it * 64;
        #pragma unroll
        for (int tt = 0; tt < 4; tt++)
          #pragma unroll
          for (int r = 0; r < 4; r++) {
            int tl = 32 * (tt >> 1) + 8 * g + 4 * (tt & 1) + r;
            if (mask[(size_t)(b * SS + q0 + qb * 16 + q) * SS + t0 + tl] == 0)
              s4[tt][r] = -1e30f;
          }
      }

      #pragma unroll
      for (int kk = 0; kk < 2; kk++) {
        bf16x8 f;
        #pragma unroll
        for (int j = 0; j < 8; j++)
          f[j] = (bf16)fexp2(s4[2 * kk + (j >> 2)][j & 3]);
        pb[qb][kk] = f;
      }
      ls[qb] = __builtin_amdgcn_mfma_f32_16x16x32_bf16(ones, pb[qb][0], ls[qb], 0, 0, 0);
      ls[qb] = __builtin_amdgcn_mfma_f32_16x16x32_bf16(ones, pb[qb][1], ls[qb], 0, 0, 0);
    }

    __builtin_amdgcn_s_setprio(1);
    #pragma unroll
    for (int kk = 0; kk < 2; kk++) {
      int cc = kk * 4 + g;
      #pragma unroll
      for (int n = 0; n < 4; n++) {
        int vrow = n * 16 + q;
        int vsl = cc ^ (q & 7);
        bf16x8 av = *(const bf16x8*)(&vs[vrow * 64 + vsl * 8]);
        #pragma unroll
        for (int qb = 0; qb < 4; qb++)
          o[qb][n] = __builtin_amdgcn_mfma_f32_16x16x32_bf16(av, pb[qb][kk],
                                                             o[qb][n], 0, 0, 0);
      }
    }
    __builtin_amdgcn_s_setprio(0);

    asm volatile("" ::: "memory");
    __builtin_amdgcn_s_barrier();
    asm volatile("" ::: "memory");
  }

  #pragma unroll
  for (int qb = 0; qb < 4; qb++) {
    float inv = 1.0f / ls[qb][0];
    #pragma unroll
    for (int n = 0; n < 4; n++) {
      bf16x4 ov;
      #pragma unroll
      for (int r = 0; r < 4; r++) ov[r] = (bf16)(o[qb][n][r] * inv);
      *(bf16x4*)&att[(size_t)(b * SS + q0 + qb * 16 + q) * DD + h * 64 +
                     n * 16 + g * 4] = ov;
    }
  }
}

// ---------------- launch ----------------
extern "C" void kernel_launch(void* const* d_in, const int* in_sizes, int n_in,
                              void* d_out, int out_size, void* d_ws, size_t ws_size,
                              hipStream_t stream) {
  const float* x = (const float*)d_in[0];
  const int* mask = (const int*)d_in[1];
  const float* Wq = (const float*)d_in[2];
  const float* bq = (const float*)d_in[3];
  const float* Wk = (const float*)d_in[4];
  const float* bk = (const float*)d_in[5];
  const float* Wv = (const float*)d_in[6];
  const float* bv = (const float*)d_in[7];
  const float* Wo = (const float*)d_in[8];
  const float* bo = (const float*)d_in[9];
  float* out = (float*)d_out;

  char* p = (char*)d_ws;
  const size_t MB16 = (size_t)MM * DD * 2;        // 16 MiB
  bf16* xb = (bf16*)p;   p += MB16;               // reused as `att` later
  bf16* QKV = (bf16*)p;  p += (size_t)MM * LDQ * 2;  // 48 MiB (V third unused)
  bf16* Vt = (bf16*)p;   p += MB16;
  bf16* Wt_all = (bf16*)p; p += (size_t)3072 * DD * 2;  // Wq|Wk|Wv transposed
  bf16* Wot = (bf16*)p;  p += (size_t)DD * DD * 2;
  float* ball = (float*)p; p += 3072 * 4;
  int* flag = (int*)p;
  bf16* att = xb;  // xb dead after QKV projection

  // 1) fused prep: wtrans x4 (1024 blocks) | cvt_x (4096) | bias+flag (12)
  prep<<<5132, 256, 0, stream>>>(x, xb, Wq, Wk, Wv, Wo, Wt_all, Wot,
                                 bq, bk, bv, ball, flag);
  // 2) QKV projection: 256^2 8-phase + transposed-V write + in-loop mask scan
  gemm_qkv_8ph<<<384, 512, 0, stream>>>(xb, Wt_all, ball, QKV, Vt,
                                        (const int4*)mask, flag);
  // 3) attention (16x16, proven R6 config)
  attn_fwd<<<dim3(BB * HH, SS / 256), 256, 0, stream>>>(QKV, Vt, mask, flag, att);
  // 4) output projection (m97 128^2 structure)
  gemm_out<<<dim3(64, 8), 256, 0, stream>>>(att, Wot, bo, out);
}

// Round 13
// 166.339 us; speedup vs baseline: 1.1777x; 1.1777x over previous
//
#include <hip/hip_runtime.h>
#include <hip/hip_bf16.h>

typedef __bf16 bf16;
typedef __bf16 bf16x4 __attribute__((ext_vector_type(4)));
typedef __bf16 bf16x8 __attribute__((ext_vector_type(8)));
typedef float f32x4 __attribute__((ext_vector_type(4)));

#define AS1 __attribute__((address_space(1)))
#define AS3 __attribute__((address_space(3)))

__device__ __forceinline__ void gload_lds16(const void* g, void* l) {
  __builtin_amdgcn_global_load_lds((const AS1 void*)g, (AS3 void*)l, 16, 0, 0);
}

__device__ __forceinline__ float fexp2(float x) {
#if __has_builtin(__builtin_amdgcn_exp2f)
  return __builtin_amdgcn_exp2f(x);
#else
  return exp2f(x);
#endif
}

// ---------------- problem constants ----------------
#define BB 4
#define SS 2048
#define DD 1024
#define HH 16
#define MM (BB*SS)          // 8192 rows
#define LDQ 3072            // QKV fused row stride
#define NT (SS/64)          // K/V tiles per attention pass
// log2(e) / sqrt(64)  -- folded into Wq,bq so softmax runs in exp2 domain
#define QSCALE 0.18033688011112042f

// ---------------- fused prep kernel ----------------
// wtrans blocks FIRST (heavier; avoid forming the kernel's tail), then cvt_x,
// then bias concat + flag init.
__global__ __launch_bounds__(256) void prep(
    const float* __restrict__ x, bf16* __restrict__ xb,
    const float* __restrict__ Wq, const float* __restrict__ Wk,
    const float* __restrict__ Wv, const float* __restrict__ Wo,
    bf16* __restrict__ WtQKV, bf16* __restrict__ Wto,
    const float* __restrict__ bq, const float* __restrict__ bk,
    const float* __restrict__ bv, float* __restrict__ ball,
    int* __restrict__ flag) {
  __shared__ float t[64][65];
  const int bid = blockIdx.x;
  if (bid < 1024) {            // ---- wtrans ----
    int id = bid;
    int which = id >> 8;
    int bi = (id >> 4) & 15, bj = id & 15;   // bi: k-tile, bj: n-tile
    const float* W = which == 0 ? Wq : which == 1 ? Wk : which == 2 ? Wv : Wo;
    bf16* Wt = which < 3 ? WtQKV + (size_t)which * 1024 * DD : Wto;
    const float scale = (which == 0) ? QSCALE : 1.0f;
    for (int c = 0; c < 16; c++) {
      int idx = threadIdx.x + c * 256;
      int r = idx >> 6, col = idx & 63;
      t[r][col] = W[(size_t)(bi * 64 + r) * DD + bj * 64 + col];
    }
    __syncthreads();
    for (int c = 0; c < 16; c++) {
      int idx = threadIdx.x + c * 256;
      int rn = idx >> 6, ck = idx & 63;
      Wt[(size_t)(bj * 64 + rn) * DD + bi * 64 + ck] = (bf16)(t[ck][rn] * scale);
    }
  } else if (bid < 5120) {     // ---- cvt_x ----
    int i = ((bid - 1024) * 256 + threadIdx.x) * 8;
    float4 a = *(const float4*)&x[i];
    float4 b = *(const float4*)&x[i + 4];
    bf16x8 o;
    o[0] = (bf16)a.x; o[1] = (bf16)a.y; o[2] = (bf16)a.z; o[3] = (bf16)a.w;
    o[4] = (bf16)b.x; o[5] = (bf16)b.y; o[6] = (bf16)b.z; o[7] = (bf16)b.w;
    *(bf16x8*)&xb[i] = o;
  } else {                     // ---- bias concat + flag init ----
    int i = (bid - 5120) * 256 + threadIdx.x;
    if (i == 0) *flag = 1;
    float v = (i < 1024) ? bq[i] * QSCALE
                         : ((i < 2048) ? bk[i - 1024] : bv[i - 2048]);
    ball[i] = v;
  }
}

// ---------------- GEMM: C(M,NCOLS) = A(M,1024) @ Bt(NCOLS,1024)^T + bias ------
// m97 structure: 128x128 tile, BK=64, 4 waves, 16x16x32 bf16 MFMA,
// global_load_lds w=16 with pre-swizzled source, XOR slot swizzle on reads.
// MODE 0: f32 output (out-proj).
// MODE 2: QKV fused output (Q,K rows; V transposed into Vt) + mask all-ones
//         check INTERLEAVED into the k-loop (one int4 load per k-step, hidden
//         under the MFMA phase -> no serial scan tail; verified R9/R11).
// R12 note: 256^2 8-phase rewrite REGRESSED here (1 blk/CU at 128KB LDS ->
// 1.5-round grid tail at 384 blocks; regime mismatch) -- m97 structure is the
// measured optimum for this problem shape.
template <int MODE>
__global__ __launch_bounds__(256) void gemm_bt(const bf16* __restrict__ A,
                                               const bf16* __restrict__ Bt,
                                               const float* __restrict__ bias,
                                               void* __restrict__ Cout, int ldc,
                                               bf16* __restrict__ Vt,
                                               const int4* __restrict__ mask4,
                                               int* __restrict__ flag) {
  constexpr int K = 1024;
  constexpr int BM = 128, BN = 128, BK = 64;
  __shared__ bf16 As[BM * BK];
  __shared__ bf16 Bs[BN * BK];
  const int tid = threadIdx.x;
  const int w = tid >> 6, l = tid & 63;
  const int wm = w >> 1, wn = w & 1;
  const int by = blockIdx.x, bx = blockIdx.y;   // swapped for XCD panel reuse

  f32x4 acc[4][4] = {};

  const int sRow = l >> 3;
  const int sSlot = (l & 7) ^ sRow;   // inverse-swizzled source slot
  const bf16* aBase = A + (size_t)(by * BM + w * 32 + sRow) * K + sSlot * 8;
  const bf16* bBase = Bt + (size_t)(bx * BN + w * 32 + sRow) * K + sSlot * 8;

  // mask-scan state (MODE 2): 11 strided int4 loads spread over 16 k-steps
  const int n4 = BB * SS * SS / 4;
  int mi = (by * 24 + bx) * 256 + tid;   // grid is (64,24) for MODE 2
  int ok = 1;
  int kiter = 0;

  for (int k0 = 0; k0 < K; k0 += BK) {
    int4 mv = {1, 1, 1, 1};
    bool have = (MODE == 2) && (kiter < 11) && (mi < n4);
    if (have) mv = mask4[mi];

    #pragma unroll
    for (int c = 0; c < 4; c++) {
      gload_lds16(aBase + (size_t)(c * 8) * K + k0, &As[(w * 32 + c * 8) * BK]);
      gload_lds16(bBase + (size_t)(c * 8) * K + k0, &Bs[(w * 32 + c * 8) * BK]);
    }
    __syncthreads();
    #pragma unroll
    for (int kk = 0; kk < 2; kk++) {
      bf16x8 af[4], bfr[4];
      #pragma unroll
      for (int i = 0; i < 4; i++) {
        int row = wm * 64 + i * 16 + (l & 15);
        int sl = (kk * 4 + (l >> 4)) ^ (row & 7);
        af[i] = *(const bf16x8*)(&As[row * BK + sl * 8]);
      }
      #pragma unroll
      for (int j = 0; j < 4; j++) {
        int row = wn * 64 + j * 16 + (l & 15);
        int sl = (kk * 4 + (l >> 4)) ^ (row & 7);
        bfr[j] = *(const bf16x8*)(&Bs[row * BK + sl * 8]);
      }
      #pragma unroll
      for (int i = 0; i < 4; i++)
        #pragma unroll
        for (int j = 0; j < 4; j++)
          acc[i][j] = __builtin_amdgcn_mfma_f32_16x16x32_bf16(af[i], bfr[j],
                                                              acc[i][j], 0, 0, 0);
    }
    __syncthreads();

    if (have) {
      if (!(mv.x && mv.y && mv.z && mv.w)) ok = 0;
      mi += 1536 * 256;
    }
    kiter++;
  }

  if (MODE == 2 && bx >= 16) {
    // V columns: transposed write into Vt (packed bf16x4 along s)
    #pragma unroll
    for (int j = 0; j < 4; j++) {
      int col = bx * BN + wn * 64 + j * 16 + (l & 15);
      int n = col - 2048;
      float bb = bias[col];
      #pragma unroll
      for (int i = 0; i < 4; i++) {
        int row0 = by * BM + wm * 64 + i * 16 + (l >> 4) * 4;
        int b_ = row0 >> 11;
        int s0 = row0 & 2047;
        bf16x4 vv;
        #pragma unroll
        for (int r = 0; r < 4; r++) vv[r] = (bf16)(acc[i][j][r] + bb);
        *(bf16x4*)&Vt[(size_t)(b_ * 1024 + n) * SS + s0] = vv;
      }
    }
  } else {
    #pragma unroll
    for (int j = 0; j < 4; j++) {
      int col = bx * BN + wn * 64 + j * 16 + (l & 15);
      float bb = bias[col];
      #pragma unroll
      for (int i = 0; i < 4; i++) {
        int row0 = by * BM + wm * 64 + i * 16 + (l >> 4) * 4;
        #pragma unroll
        for (int r = 0; r < 4; r++) {
          float v = acc[i][j][r] + bb;
          if (MODE == 2)
            ((bf16*)Cout)[(size_t)(row0 + r) * ldc + col] = (bf16)v;
          else
            ((float*)Cout)[(size_t)(row0 + r) * ldc + col] = v;
        }
      }
    }
  }

  if (MODE == 2) {
    if (__ballot(!ok)) {
      if ((tid & 63) == 0) atomicAnd(flag, 0);
    }
  }
}

// ---------------- fused flash attention (R6 structure, proven 77 us) ---------
// grid (B*H, S/256): 4 waves x 64 q-rows (4 q-blocks) = 256 q/block; 2 blk/CU.
// R7(2-wave)/R10(4-blk) occupancy experiments both regressed: this config is
// the measured optimum (LDS amortization x L2 footprint x TLP).
// K/V 64-wide tiles double-buffered (counted vmcnt(4) + raw barriers).
// Swapped-operand QK^T with PERMUTED K rows in LDS (t=32kk+8g+4c+r at LDS row
// m=32kk+16c+4g+r): lane (g,q)'s S^T outputs ARE its PV B-fragment
// (frag j = s4[2kk+(j>>2)][j&3] <-> t=32kk+8g+j) -> P never touches LDS.
// K fragments register-cached once per tile, reused by all 4 q-blocks.
// Max-free softmax in exp2 domain (scores pre-scaled via Wq); denominator via
// ones-MFMA (column sums replicated -> no add chains, no end shuffles).
__global__ __launch_bounds__(256, 2) void attn_fwd(const bf16* __restrict__ QKV,
                                                   const bf16* __restrict__ Vt,
                                                   const int* __restrict__ mask,
                                                   const int* __restrict__ flag,
                                                   bf16* __restrict__ att) {
  __shared__ bf16 Ks[2][64 * 64];
  __shared__ bf16 Vs[2][64 * 64];
  const int tid = threadIdx.x, w = tid >> 6, l = tid & 63;
  const int g = l >> 4, q = l & 15;
  const int bh = blockIdx.x, b = bh >> 4, h = bh & 15;
  const int q0 = blockIdx.y * 256 + w * 64;   // this wave's 64 q-rows
  const bool allones = (*flag != 0);

  // Q B-fragments for four 16-col q-blocks (col=q, k = kk*32 + g*8 + j)
  bf16x8 bq[4][2];
  #pragma unroll
  for (int qb = 0; qb < 4; qb++) {
    const bf16* qptr =
        QKV + (size_t)(b * SS + q0 + qb * 16 + q) * LDQ + h * 64 + g * 8;
    bq[qb][0] = *(const bf16x8*)qptr;
    bq[qb][1] = *(const bf16x8*)(qptr + 32);
  }

  bf16x8 ones;
  #pragma unroll
  for (int j = 0; j < 8; j++) ones[j] = (bf16)1.0f;

  f32x4 o[4][4] = {};
  f32x4 ls[4] = {};   // softmax denominators (all 4 components identical)

  const int sSlot = (l & 7) ^ ((l >> 3) & 7);
  // permuted K-row source: gload block B8 = 2w+c covers LDS rows B8*8..+7;
  // lane fetches global tile-row t = 32*(B8>>2)+16*(B8&1)+4*((B8>>1)&1)
  //                                  + 8*(l>>5) + ((l>>3)&3)
  const bf16* kPtr[2];
  #pragma unroll
  for (int c = 0; c < 2; c++) {
    int B8 = 2 * w + c;
    int tl = 32 * (B8 >> 2) + 16 * (B8 & 1) + 4 * ((B8 >> 1) & 1) +
             8 * (l >> 5) + ((l >> 3) & 3);
    kPtr[c] = QKV + (size_t)(b * SS + tl) * LDQ + 1024 + h * 64 + sSlot * 8;
  }
  const bf16* vBase =
      Vt + (size_t)(b * 1024 + h * 64 + w * 16 + (l >> 3)) * SS + sSlot * 8;

  // prologue: stage tile 0 into buffer 0
  gload_lds16(kPtr[0], &Ks[0][(2 * w + 0) * 8 * 64]);
  gload_lds16(kPtr[1], &Ks[0][(2 * w + 1) * 8 * 64]);
  gload_lds16(vBase, &Vs[0][(w * 16) * 64]);
  gload_lds16(vBase + (size_t)8 * SS, &Vs[0][(w * 16 + 8) * 64]);

  for (int it = 0; it < NT; ++it) {
    const int cur = it & 1;
    if (it + 1 < NT) {   // stage next tile, wait only for cur's loads
      const int t1 = (it + 1) * 64;
      gload_lds16(kPtr[0] + (size_t)t1 * LDQ, &Ks[cur ^ 1][(2 * w + 0) * 8 * 64]);
      gload_lds16(kPtr[1] + (size_t)t1 * LDQ, &Ks[cur ^ 1][(2 * w + 1) * 8 * 64]);
      gload_lds16(vBase + t1, &Vs[cur ^ 1][(w * 16) * 64]);
      gload_lds16(vBase + (size_t)8 * SS + t1, &Vs[cur ^ 1][(w * 16 + 8) * 64]);
      asm volatile("s_waitcnt vmcnt(4)" ::: "memory");
    } else {
      asm volatile("s_waitcnt vmcnt(0)" ::: "memory");
    }
    __builtin_amdgcn_s_barrier();
    asm volatile("" ::: "memory");

    const bf16* ks = Ks[cur];
    const bf16* vs = Vs[cur];

    // register-cache the 8 K fragments once; reused by all 4 q-blocks
    bf16x8 af[4][2];
    #pragma unroll
    for (int tt = 0; tt < 4; tt++) {
      int row = tt * 16 + q;
      af[tt][0] = *(const bf16x8*)(&ks[row * 64 + (g ^ (q & 7)) * 8]);
      af[tt][1] = *(const bf16x8*)(&ks[row * 64 + (((4 + g) ^ (q & 7))) * 8]);
    }

    // per q-block: S^T = K Q^T -> softmax -> PV B-fragments + ones-MFMA lsum.
    // Straight-line region, no fences: qb-independent work overlaps pipes.
    bf16x8 pb[4][2];
    #pragma unroll
    for (int qb = 0; qb < 4; qb++) {
      f32x4 s4[4];
      #pragma unroll
      for (int tt = 0; tt < 4; tt++) {
        f32x4 z = {};
        z = __builtin_amdgcn_mfma_f32_16x16x32_bf16(af[tt][0], bq[qb][0], z, 0, 0, 0);
        z = __builtin_amdgcn_mfma_f32_16x16x32_bf16(af[tt][1], bq[qb][1], z, 0, 0, 0);
        s4[tt] = z;
      }

      if (!allones) {  // masked fallback; m-row -> actual t: t=32kk+8g+4c+r
        const int t0 = it * 64;
        #pragma unroll
        for (int tt = 0; tt < 4; tt++)
          #pragma unroll
          for (int r = 0; r < 4; r++) {
            int tl = 32 * (tt >> 1) + 8 * g + 4 * (tt & 1) + r;
            if (mask[(size_t)(b * SS + q0 + qb * 16 + q) * SS + t0 + tl] == 0)
              s4[tt][r] = -1e30f;
          }
      }

      // max-free softmax; build PV B-fragments directly from s4
      #pragma unroll
      for (int kk = 0; kk < 2; kk++) {
        bf16x8 f;
        #pragma unroll
        for (int j = 0; j < 8; j++)
          f[j] = (bf16)fexp2(s4[2 * kk + (j >> 2)][j & 3]);
        pb[qb][kk] = f;
      }
      // denominator: ls[qb] += ones @ P  (column sums, replicated rows)
      ls[qb] = __builtin_amdgcn_mfma_f32_16x16x32_bf16(ones, pb[qb][0], ls[qb], 0, 0, 0);
      ls[qb] = __builtin_amdgcn_mfma_f32_16x16x32_bf16(ones, pb[qb][1], ls[qb], 0, 0, 0);
    }

    // ---- O^T += V^T P^T (each V read feeds 4 q-blocks) ----
    __builtin_amdgcn_s_setprio(1);
    #pragma unroll
    for (int kk = 0; kk < 2; kk++) {
      int cc = kk * 4 + g;
      #pragma unroll
      for (int n = 0; n < 4; n++) {
        int vrow = n * 16 + q;
        int vsl = cc ^ (q & 7);
        bf16x8 av = *(const bf16x8*)(&vs[vrow * 64 + vsl * 8]);
        #pragma unroll
        for (int qb = 0; qb < 4; qb++)
          o[qb][n] = __builtin_amdgcn_mfma_f32_16x16x32_bf16(av, pb[qb][kk],
                                                             o[qb][n], 0, 0, 0);
      }
    }
    __builtin_amdgcn_s_setprio(0);

    asm volatile("" ::: "memory");
    __builtin_amdgcn_s_barrier();
    asm volatile("" ::: "memory");
  }

  // normalize + store (ls already summed over ALL t and all lane-groups)
  #pragma unroll
  for (int qb = 0; qb < 4; qb++) {
    float inv = 1.0f / ls[qb][0];
    #pragma unroll
    for (int n = 0; n < 4; n++) {
      bf16x4 ov;
      #pragma unroll
      for (int r = 0; r < 4; r++) ov[r] = (bf16)(o[qb][n][r] * inv);
      *(bf16x4*)&att[(size_t)(b * SS + q0 + qb * 16 + q) * DD + h * 64 +
                     n * 16 + g * 4] = ov;
    }
  }
}

// ---------------- launch ----------------
extern "C" void kernel_launch(void* const* d_in, const int* in_sizes, int n_in,
                              void* d_out, int out_size, void* d_ws, size_t ws_size,
                              hipStream_t stream) {
  const float* x = (const float*)d_in[0];
  const int* mask = (const int*)d_in[1];
  const float* Wq = (const float*)d_in[2];
  const float* bq = (const float*)d_in[3];
  const float* Wk = (const float*)d_in[4];
  const float* bk = (const float*)d_in[5];
  const float* Wv = (const float*)d_in[6];
  const float* bv = (const float*)d_in[7];
  const float* Wo = (const float*)d_in[8];
  const float* bo = (const float*)d_in[9];
  float* out = (float*)d_out;

  char* p = (char*)d_ws;
  const size_t MB16 = (size_t)MM * DD * 2;        // 16 MiB
  bf16* xb = (bf16*)p;   p += MB16;               // reused as `att` later
  bf16* QKV = (bf16*)p;  p += (size_t)MM * LDQ * 2;  // 48 MiB (V third unused)
  bf16* Vt = (bf16*)p;   p += MB16;
  bf16* Wt_all = (bf16*)p; p += (size_t)3072 * DD * 2;  // Wq|Wk|Wv transposed
  bf16* Wot = (bf16*)p;  p += (size_t)DD * DD * 2;
  float* ball = (float*)p; p += 3072 * 4;
  int* flag = (int*)p;
  bf16* att = xb;  // xb dead after QKV projection

  // 1) fused prep: wtrans x4 (1024 blocks) | cvt_x (4096) | bias+flag (12)
  prep<<<5132, 256, 0, stream>>>(x, xb, Wq, Wk, Wv, Wo, Wt_all, Wot,
                                 bq, bk, bv, ball, flag);
  // 2) fused QKV projection + transposed-V write + in-loop mask scan
  gemm_bt<2><<<dim3(64, 24), 256, 0, stream>>>(xb, Wt_all, ball, QKV, LDQ,
                                               Vt, (const int4*)mask, flag);
  // 3) attention (16x16, proven R6 config)
  attn_fwd<<<dim3(BB * HH, SS / 256), 256, 0, stream>>>(QKV, Vt, mask, flag, att);
  // 4) output projection
  gemm_bt<0><<<dim3(64, 8), 256, 0, stream>>>(att, Wot, bo, out, DD,
                                              Vt, (const int4*)mask, flag);
}